// Round 1
// baseline (98.043 us; speedup 1.0000x reference)
//
#include <hip/hip_runtime.h>

#define Gn    32
#define NVn   64
#define Hn    256
#define NROWS (Gn * NVn)   // 2048

// ---------------------------------------------------------------------------
// Kernel A: dual GEMM (C = Z * W^T + b) with fused exp(-x) epilogue.
//   which==0: ec[n][o] = exp(-(dot(z[n],Wc[o]) + bc[o]))
//   which==1: ey[n][o] = exp(-(dot(z[n],Wy[o]) + by[o] + (m[n]-1)*1e10))
//             (masked rows -> exp(+1e10) = +inf -> sigmoid term 0)
// Tiles: 64(n) x 64(o), K-chunk 32, thread tile 4x4, LDS stored transposed
// with row stride 68 floats (16B aligned for ds_read_b128).
// ---------------------------------------------------------------------------
__global__ __launch_bounds__(256) void gemm_exp_kernel(
    const float* __restrict__ z,
    const float* __restrict__ mask,
    const float* __restrict__ Wc, const float* __restrict__ bc,
    const float* __restrict__ Wy, const float* __restrict__ by,
    float* __restrict__ ws)
{
    const int n0    = blockIdx.x * 64;
    const int o0    = blockIdx.y * 64;
    const int which = blockIdx.z;
    const float* __restrict__ W    = which ? Wy : Wc;
    const float* __restrict__ bias = which ? by : bc;
    float* __restrict__ dst = ws + (size_t)which * NROWS * Hn;

    __shared__ float Zs[32][68];   // [k][n], transposed
    __shared__ float Ws[32][68];   // [k][o], transposed

    const int t  = threadIdx.x;
    const int tx = t & 15;   // o-dim
    const int ty = t >> 4;   // n-dim

    float acc[4][4];
#pragma unroll
    for (int r = 0; r < 4; ++r)
#pragma unroll
        for (int s = 0; s < 4; ++s) acc[r][s] = 0.f;

    for (int kk = 0; kk < Hn; kk += 32) {
#pragma unroll
        for (int l = 0; l < 2; ++l) {
            const int v   = t + l * 256;   // 0..511
            const int row = v >> 3;        // 0..63
            const int k4  = v & 7;         // 0..7 (float4 index within k-chunk)
            const float4 zv = *(const float4*)(z + (size_t)(n0 + row) * Hn + kk + k4 * 4);
            Zs[k4*4+0][row] = zv.x; Zs[k4*4+1][row] = zv.y;
            Zs[k4*4+2][row] = zv.z; Zs[k4*4+3][row] = zv.w;
            const float4 wv = *(const float4*)(W + (size_t)(o0 + row) * Hn + kk + k4 * 4);
            Ws[k4*4+0][row] = wv.x; Ws[k4*4+1][row] = wv.y;
            Ws[k4*4+2][row] = wv.z; Ws[k4*4+3][row] = wv.w;
        }
        __syncthreads();
#pragma unroll
        for (int k = 0; k < 32; ++k) {
            const float4 a = *(const float4*)&Zs[k][ty * 4];
            const float4 b = *(const float4*)&Ws[k][tx * 4];
            acc[0][0] += a.x * b.x; acc[0][1] += a.x * b.y; acc[0][2] += a.x * b.z; acc[0][3] += a.x * b.w;
            acc[1][0] += a.y * b.x; acc[1][1] += a.y * b.y; acc[1][2] += a.y * b.z; acc[1][3] += a.y * b.w;
            acc[2][0] += a.z * b.x; acc[2][1] += a.z * b.y; acc[2][2] += a.z * b.z; acc[2][3] += a.z * b.w;
            acc[3][0] += a.w * b.x; acc[3][1] += a.w * b.y; acc[3][2] += a.w * b.z; acc[3][3] += a.w * b.w;
        }
        __syncthreads();
    }

    const float4 b4 = *(const float4*)(bias + o0 + tx * 4);
#pragma unroll
    for (int r = 0; r < 4; ++r) {
        const int n = n0 + ty * 4 + r;
        float mt = 0.f;
        if (which) mt = (mask[n] - 1.f) * 1e10f;
        float4 o;
        o.x = __expf(-(acc[r][0] + b4.x + mt));
        o.y = __expf(-(acc[r][1] + b4.y + mt));
        o.z = __expf(-(acc[r][2] + b4.z + mt));
        o.w = __expf(-(acc[r][3] + b4.w + mt));
        *(float4*)(dst + (size_t)n * Hn + o0 + tx * 4) = o;
    }
}

// ---------------------------------------------------------------------------
// Kernel B: out[g,i,o] = m_i/denom_g * sum_{j active} 1/(1 + ec[g,i,o]*ey[g,j,o])
// Block = (g, quad of i). Thread t: i = iq*4 + (t>>6), columns oc..oc+3.
// Masked j skipped with a wave-uniform branch (j is uniform across the block).
// ---------------------------------------------------------------------------
__global__ __launch_bounds__(256) void pair_kernel(
    const float* __restrict__ mask,
    const float* __restrict__ ws,
    float* __restrict__ out)
{
    const float* __restrict__ ec = ws;
    const float* __restrict__ ey = ws + (size_t)NROWS * Hn;

    const int g  = blockIdx.x >> 4;   // 512 blocks: 32 g * 16 iq
    const int iq = blockIdx.x & 15;
    const int t  = threadIdx.x;
    const int i  = iq * 4 + (t >> 6);
    const int oc = (t & 63) * 4;

    __shared__ float ms[64];
    if (t < 64) ms[t] = mask[g * NVn + t];
    __syncthreads();

    float denom = 0.f;
#pragma unroll
    for (int j = 0; j < NVn; ++j) denom += ms[j];

    const int row_i = g * NVn + i;
    const float4 ec4 = *(const float4*)(ec + (size_t)row_i * Hn + oc);

    float ax = 0.f, ay = 0.f, az = 0.f, aw = 0.f;
    for (int j = 0; j < NVn; ++j) {
        if (ms[j] == 0.f) continue;   // uniform across block
        const float4 e4 = *(const float4*)(ey + (size_t)(g * NVn + j) * Hn + oc);
        ax += __builtin_amdgcn_rcpf(1.f + ec4.x * e4.x);
        ay += __builtin_amdgcn_rcpf(1.f + ec4.y * e4.y);
        az += __builtin_amdgcn_rcpf(1.f + ec4.z * e4.z);
        aw += __builtin_amdgcn_rcpf(1.f + ec4.w * e4.w);
    }

    const float scale = ms[i] / denom;
    float4 o4;
    o4.x = ax * scale; o4.y = ay * scale; o4.z = az * scale; o4.w = aw * scale;
    *(float4*)(out + (size_t)row_i * Hn + oc) = o4;
}

extern "C" void kernel_launch(void* const* d_in, const int* in_sizes, int n_in,
                              void* d_out, int out_size, void* d_ws, size_t ws_size,
                              hipStream_t stream) {
    // inputs: 0=num_graphs(int), 1=nv(int), 2=z, 3=mask, 4=Wc, 5=bc, 6=Wy, 7=by
    const float* z    = (const float*)d_in[2];
    const float* mask = (const float*)d_in[3];
    const float* Wc   = (const float*)d_in[4];
    const float* bc   = (const float*)d_in[5];
    const float* Wy   = (const float*)d_in[6];
    const float* by   = (const float*)d_in[7];
    float* out = (float*)d_out;
    float* ws  = (float*)d_ws;   // needs 2 * 2048 * 256 * 4 B = 4 MiB

    dim3 gridA(NROWS / 64, Hn / 64, 2);   // 32 x 4 x 2 = 256 blocks
    gemm_exp_kernel<<<gridA, 256, 0, stream>>>(z, mask, Wc, bc, Wy, by, ws);

    pair_kernel<<<NROWS / 4, 256, 0, stream>>>(mask, ws, out);
}

// Round 2
// 87.425 us; speedup vs baseline: 1.1215x; 1.1215x over previous
//
#include <hip/hip_runtime.h>

#define Gn    32
#define NVn   64
#define Hn    256
#define NROWS (Gn * NVn)   // 2048

// ---------------------------------------------------------------------------
// Kernel A: dual GEMM (C = Z * W^T, + bias in epilogue) with fused exp(-x).
//   which==0: ec[n][o] = exp(-(dot(z[n],Wc[o]) + bc[o]))
//   which==1: ey[n][o] = exp(-(dot(z[n],Wy[o]) + by[o]))
// No mask term needed: kernel B skips masked rows on both i and j sides.
// Tile 64(n) x 64(o), K-chunk 32, 512 threads (8 waves/CU), thread tile 2x4.
// Register-prefetch pipeline: next chunk's global loads issue before compute.
// ---------------------------------------------------------------------------
__global__ __launch_bounds__(512) void gemm_exp_kernel(
    const float* __restrict__ z,
    const float* __restrict__ Wc, const float* __restrict__ bc,
    const float* __restrict__ Wy, const float* __restrict__ by,
    float* __restrict__ ws)
{
    const int n0    = blockIdx.x * 64;
    const int o0    = blockIdx.y * 64;
    const int which = blockIdx.z;
    const float* __restrict__ W    = which ? Wy : Wc;
    const float* __restrict__ bias = which ? by : bc;
    float* __restrict__ dst = ws + (size_t)which * NROWS * Hn;

    __shared__ float Zs[32][68];   // [k][n] transposed; stride 68 = 16B-aligned rows
    __shared__ float Ws_[32][68];  // [k][o] transposed

    const int t  = threadIdx.x;    // 0..511
    const int tx = t & 15;         // o-quad   (16)
    const int ty = t >> 4;         // n-pair   (32)

    // staging assignment: 64 rows x 8 k-quads
    const int srow = t >> 3;       // 0..63
    const int sk4  = t & 7;        // 0..7
    const float* zsrc = z + (size_t)(n0 + srow) * Hn + sk4 * 4;
    const float* wsrc = W + (size_t)(o0 + srow) * Hn + sk4 * 4;

    float4 zr = *(const float4*)zsrc;
    float4 wr = *(const float4*)wsrc;

    float acc[2][4];
#pragma unroll
    for (int r = 0; r < 2; ++r)
#pragma unroll
        for (int s = 0; s < 4; ++s) acc[r][s] = 0.f;

    for (int kk = 0; kk < 8; ++kk) {
        Zs[sk4*4+0][srow] = zr.x; Zs[sk4*4+1][srow] = zr.y;
        Zs[sk4*4+2][srow] = zr.z; Zs[sk4*4+3][srow] = zr.w;
        Ws_[sk4*4+0][srow] = wr.x; Ws_[sk4*4+1][srow] = wr.y;
        Ws_[sk4*4+2][srow] = wr.z; Ws_[sk4*4+3][srow] = wr.w;
        __syncthreads();

        if (kk < 7) {   // prefetch next chunk while computing this one
            zr = *(const float4*)(zsrc + (kk + 1) * 32);
            wr = *(const float4*)(wsrc + (kk + 1) * 32);
        }

#pragma unroll
        for (int k = 0; k < 32; ++k) {
            const float2 a = *(const float2*)&Zs[k][ty * 2];
            const float4 b = *(const float4*)&Ws_[k][tx * 4];
            acc[0][0] += a.x * b.x; acc[0][1] += a.x * b.y;
            acc[0][2] += a.x * b.z; acc[0][3] += a.x * b.w;
            acc[1][0] += a.y * b.x; acc[1][1] += a.y * b.y;
            acc[1][2] += a.y * b.z; acc[1][3] += a.y * b.w;
        }
        __syncthreads();
    }

    const float4 b4 = *(const float4*)(bias + o0 + tx * 4);
#pragma unroll
    for (int r = 0; r < 2; ++r) {
        const int n = n0 + ty * 2 + r;
        float4 o;
        o.x = __expf(-(acc[r][0] + b4.x));
        o.y = __expf(-(acc[r][1] + b4.y));
        o.z = __expf(-(acc[r][2] + b4.z));
        o.w = __expf(-(acc[r][3] + b4.w));
        *(float4*)(dst + (size_t)n * Hn + o0 + tx * 4) = o;
    }
}

// ---------------------------------------------------------------------------
// Kernel B: out[g,i,o] = (m_i/denom_g) * sum_{j active} 1/(1 + ec[g,i,o]*ey[g,j,o])
// Block = (g, octet of i), 512 threads. i = i0 + wave_id (wave-uniform):
// masked-i waves store zeros and exit. Active-j indices compacted to LDS via
// ballot so the j-loop is unguarded -> unrollable, loads independent.
// ---------------------------------------------------------------------------
__global__ __launch_bounds__(512) void pair_kernel(
    const float* __restrict__ mask,
    const float* __restrict__ ws,
    float* __restrict__ out)
{
    const float* __restrict__ ec = ws;
    const float* __restrict__ ey = ws + (size_t)NROWS * Hn;

    const int g  = blockIdx.x >> 3;        // 256 blocks: 32 g * 8 octets
    const int i0 = (blockIdx.x & 7) * 8;
    const int t  = threadIdx.x;
    const int i  = i0 + (t >> 6);          // wave-uniform
    const int oc = (t & 63) * 4;

    __shared__ int act[64];
    __shared__ int cnt_s;

    if (t < 64) {                          // exactly wave 0
        const float m = mask[g * NVn + t];
        const unsigned long long b = __ballot(m != 0.f);
        const int below = __popcll(b & ((1ull << t) - 1ull));
        if (m != 0.f) act[below] = t;
        if (t == 0) cnt_s = (int)__popcll(b);
    }
    __syncthreads();
    const int cnt = cnt_s;

    const int row_i = g * NVn + i;
    float* po = out + (size_t)row_i * Hn + oc;

    const float mi = mask[row_i];
    if (mi == 0.f) {                       // wave-uniform: whole wave exits
        float4 zr; zr.x = zr.y = zr.z = zr.w = 0.f;
        *(float4*)po = zr;
        return;
    }

    const float4 ec4 = *(const float4*)(ec + (size_t)row_i * Hn + oc);
    const float* eyg = ey + (size_t)g * NVn * Hn + oc;

    float ax = 0.f, ay = 0.f, az = 0.f, aw = 0.f;
#pragma unroll 4
    for (int jj = 0; jj < cnt; ++jj) {
        const int j = act[jj];
        const float4 e4 = *(const float4*)(eyg + (size_t)j * Hn);
        ax += __builtin_amdgcn_rcpf(__builtin_fmaf(ec4.x, e4.x, 1.f));
        ay += __builtin_amdgcn_rcpf(__builtin_fmaf(ec4.y, e4.y, 1.f));
        az += __builtin_amdgcn_rcpf(__builtin_fmaf(ec4.z, e4.z, 1.f));
        aw += __builtin_amdgcn_rcpf(__builtin_fmaf(ec4.w, e4.w, 1.f));
    }

    const float s = 1.f / (float)cnt;      // m_i = 1 here; denom = popcount
    float4 o4;
    o4.x = ax * s; o4.y = ay * s; o4.z = az * s; o4.w = aw * s;
    *(float4*)po = o4;
}

extern "C" void kernel_launch(void* const* d_in, const int* in_sizes, int n_in,
                              void* d_out, int out_size, void* d_ws, size_t ws_size,
                              hipStream_t stream) {
    // inputs: 0=num_graphs, 1=nv, 2=z, 3=mask, 4=Wc, 5=bc, 6=Wy, 7=by
    const float* z    = (const float*)d_in[2];
    const float* mask = (const float*)d_in[3];
    const float* Wc   = (const float*)d_in[4];
    const float* bc   = (const float*)d_in[5];
    const float* Wy   = (const float*)d_in[6];
    const float* by   = (const float*)d_in[7];
    float* out = (float*)d_out;
    float* ws  = (float*)d_ws;   // uses 2 * 2048 * 256 * 4 B = 4 MiB

    dim3 gridA(NROWS / 64, Hn / 64, 2);   // 32 x 4 x 2 = 256 blocks, 512 thr
    gemm_exp_kernel<<<gridA, 512, 0, stream>>>(z, Wc, bc, Wy, by, ws);

    pair_kernel<<<Gn * 8, 512, 0, stream>>>(mask, ws, out);
}

// Round 3
// 81.005 us; speedup vs baseline: 1.2103x; 1.0793x over previous
//
#include <hip/hip_runtime.h>

#define Gn    32
#define NVn   64
#define Hn    256
#define NROWS (Gn * NVn)   // 2048

typedef __attribute__((ext_vector_type(8))) short  bf16x8;
typedef __attribute__((ext_vector_type(4))) float  f32x4;

__device__ inline unsigned short f2bf(float f) {
    unsigned int u = __builtin_bit_cast(unsigned int, f);
    return (unsigned short)((u + 0x7FFFu + ((u >> 16) & 1u)) >> 16);
}

// ---------------------------------------------------------------------------
// Kernel A: dual GEMM via bf16 MFMA, fused exp(-x) epilogue.
//   which==0: ec[n][o] = exp(-(dot(z[n],Wc[o]) + bc[o]))
//   which==1: ey[n][o] = exp(-(dot(z[n],Wy[o]) + by[o]))
// Block: 64(n) x 64(o) tile, 512 threads (8 waves). Wave w computes the
// 16-row n-strip (w&3) x 32-col o-half (w>>2): 2 MFMA tiles per K-chunk.
// K-chunk 32. fp32 global -> bf16 LDS (row stride 40 = 80 B: 16B-aligned
// b128 rows, disjoint 4-bank windows -> bank-floor). Threads 0..255 stage Z,
// 256..511 stage W; next chunk prefetched into registers during compute.
// Fragment maps (m89-verified): A row=lane&15,k=quad*8+j; C/D col=lane&15,
// row=quad*4+reg.
// ---------------------------------------------------------------------------
__global__ __launch_bounds__(512) void gemm_exp_mfma(
    const float* __restrict__ z,
    const float* __restrict__ Wc, const float* __restrict__ bc,
    const float* __restrict__ Wy, const float* __restrict__ by,
    float* __restrict__ ws)
{
    const int n0    = blockIdx.x * 64;
    const int o0    = blockIdx.y * 64;
    const int which = blockIdx.z;
    const float* __restrict__ W    = which ? Wy : Wc;
    const float* __restrict__ bias = which ? by : bc;
    float* __restrict__ dst = ws + (size_t)which * NROWS * Hn;

    __shared__ unsigned short Za[64][40];   // [n][k] bf16, pad to 40
    __shared__ unsigned short Wb[64][40];   // [o][k] bf16

    const int t    = threadIdx.x;
    const int half = t >> 8;          // 0: stage Z, 1: stage W
    const int tt   = t & 255;
    const int srow = tt >> 2;         // 0..63
    const int sk   = (tt & 3) * 8;    // k offset: 0,8,16,24

    const float* src = half ? (W + (size_t)(o0 + srow) * Hn + sk)
                            : (z + (size_t)(n0 + srow) * Hn + sk);
    unsigned short* ldst = half ? &Wb[srow][sk] : &Za[srow][sk];

    const int wv = t >> 6;            // wave 0..7
    const int l  = t & 63;
    const int lm = l & 15;
    const int lq = l >> 4;
    const int ns = (wv & 3) * 16;     // n-strip within tile
    const int oh = (wv >> 2) * 32;    // o-half within tile

    f32x4 acc[2] = {{0.f,0.f,0.f,0.f},{0.f,0.f,0.f,0.f}};

    float4 p0 = *(const float4*)(src);
    float4 p1 = *(const float4*)(src + 4);

    for (int kk = 0; kk < 8; ++kk) {
        bf16x8 v;
        v[0] = (short)f2bf(p0.x); v[1] = (short)f2bf(p0.y);
        v[2] = (short)f2bf(p0.z); v[3] = (short)f2bf(p0.w);
        v[4] = (short)f2bf(p1.x); v[5] = (short)f2bf(p1.y);
        v[6] = (short)f2bf(p1.z); v[7] = (short)f2bf(p1.w);
        *(bf16x8*)ldst = v;
        __syncthreads();

        if (kk < 7) {   // prefetch next K-chunk while MFMAs run
            p0 = *(const float4*)(src + (kk + 1) * 32);
            p1 = *(const float4*)(src + (kk + 1) * 32 + 4);
        }

        const bf16x8 af = *(const bf16x8*)&Za[ns + lm][lq * 8];
        const bf16x8 b0 = *(const bf16x8*)&Wb[oh + lm][lq * 8];
        const bf16x8 b1 = *(const bf16x8*)&Wb[oh + 16 + lm][lq * 8];
        acc[0] = __builtin_amdgcn_mfma_f32_16x16x32_bf16(af, b0, acc[0], 0, 0, 0);
        acc[1] = __builtin_amdgcn_mfma_f32_16x16x32_bf16(af, b1, acc[1], 0, 0, 0);
        __syncthreads();
    }

#pragma unroll
    for (int ot = 0; ot < 2; ++ot) {
        const int o  = o0 + oh + ot * 16 + lm;
        const float bv = bias[o];
#pragma unroll
        for (int r = 0; r < 4; ++r) {
            const int n = n0 + ns + lq * 4 + r;
            dst[(size_t)n * Hn + o] = __expf(-(acc[ot][r] + bv));
        }
    }
}

// ---------------------------------------------------------------------------
// Kernel B: out[g,i,o] = (m_i/denom_g) * sum_{j active} 1/(1 + ec[g,i,o]*ey[g,j,o])
// Block = (g, octet of i), 512 threads. i wave-uniform: masked-i waves store
// zeros and exit. Active-j indices compacted to LDS via ballot so the j-loop
// is unguarded -> unrollable, loads independent.
// ---------------------------------------------------------------------------
__global__ __launch_bounds__(512) void pair_kernel(
    const float* __restrict__ mask,
    const float* __restrict__ ws,
    float* __restrict__ out)
{
    const float* __restrict__ ec = ws;
    const float* __restrict__ ey = ws + (size_t)NROWS * Hn;

    const int g  = blockIdx.x >> 3;        // 256 blocks: 32 g * 8 octets
    const int i0 = (blockIdx.x & 7) * 8;
    const int t  = threadIdx.x;
    const int i  = i0 + (t >> 6);          // wave-uniform
    const int oc = (t & 63) * 4;

    __shared__ int act[64];
    __shared__ int cnt_s;

    if (t < 64) {                          // exactly wave 0
        const float m = mask[g * NVn + t];
        const unsigned long long b = __ballot(m != 0.f);
        const int below = __popcll(b & ((1ull << t) - 1ull));
        if (m != 0.f) act[below] = t;
        if (t == 0) cnt_s = (int)__popcll(b);
    }
    __syncthreads();
    const int cnt = cnt_s;

    const int row_i = g * NVn + i;
    float* po = out + (size_t)row_i * Hn + oc;

    const float mi = mask[row_i];
    if (mi == 0.f) {                       // wave-uniform: whole wave exits
        float4 zr; zr.x = zr.y = zr.z = zr.w = 0.f;
        *(float4*)po = zr;
        return;
    }

    const float4 ec4 = *(const float4*)(ec + (size_t)row_i * Hn + oc);
    const float* eyg = ey + (size_t)g * NVn * Hn + oc;

    float ax = 0.f, ay = 0.f, az = 0.f, aw = 0.f;
#pragma unroll 4
    for (int jj = 0; jj < cnt; ++jj) {
        const int j = act[jj];
        const float4 e4 = *(const float4*)(eyg + (size_t)j * Hn);
        ax += __builtin_amdgcn_rcpf(__builtin_fmaf(ec4.x, e4.x, 1.f));
        ay += __builtin_amdgcn_rcpf(__builtin_fmaf(ec4.y, e4.y, 1.f));
        az += __builtin_amdgcn_rcpf(__builtin_fmaf(ec4.z, e4.z, 1.f));
        aw += __builtin_amdgcn_rcpf(__builtin_fmaf(ec4.w, e4.w, 1.f));
    }

    const float s = 1.f / (float)cnt;      // m_i = 1 here; denom = popcount
    float4 o4;
    o4.x = ax * s; o4.y = ay * s; o4.z = az * s; o4.w = aw * s;
    *(float4*)po = o4;
}

extern "C" void kernel_launch(void* const* d_in, const int* in_sizes, int n_in,
                              void* d_out, int out_size, void* d_ws, size_t ws_size,
                              hipStream_t stream) {
    // inputs: 0=num_graphs, 1=nv, 2=z, 3=mask, 4=Wc, 5=bc, 6=Wy, 7=by
    const float* z    = (const float*)d_in[2];
    const float* mask = (const float*)d_in[3];
    const float* Wc   = (const float*)d_in[4];
    const float* bc   = (const float*)d_in[5];
    const float* Wy   = (const float*)d_in[6];
    const float* by   = (const float*)d_in[7];
    float* out = (float*)d_out;
    float* ws  = (float*)d_ws;   // uses 2 * 2048 * 256 * 4 B = 4 MiB

    dim3 gridA(NROWS / 64, Hn / 64, 2);   // 32 x 4 x 2 = 256 blocks, 512 thr
    gemm_exp_mfma<<<gridA, 512, 0, stream>>>(z, Wc, bc, Wy, by, ws);

    pair_kernel<<<Gn * 8, 512, 0, stream>>>(mask, ws, out);
}